// Round 1
// baseline (1617.644 us; speedup 1.0000x reference)
//
#include <hip/hip_runtime.h>

#define N_ATOMS 131072
#define NUM_GS  128
#define HIDDEN  512
#define N_MOL   1024

#define BM      32                      // atoms per MLP block
#define NB_SIDE (N_ATOMS / BM)          // 4096 blocks per type-side

// ---- workspace layout (in 4-byte elements) ----
// [0..1]        : cntA, cntB (int, atomics)
// [16..1039]    : mol_sum  (float[1024])
// [1040..2063]  : mol_cnt  (float[1024])
// [2064..]      : perm     (int[131072])
#define WS_CNT        0
#define WS_MOLSUM     16
#define WS_MOLCNT     1040
#define WS_PERM       2064
#define WS_ZERO_BYTES (2064 * 4)

__device__ __forceinline__ float fast_tanh(float x) {
    // (e^{2x}-1)/(e^{2x}+1), clamped so __expf never overflows. rel err ~1e-6.
    x = fminf(20.f, fmaxf(-20.f, x));
    float e = __expf(2.f * x);
    return (e - 1.f) / (e + 1.f);
}

// ---------------------------------------------------------------------------
// Kernel 1: partition atoms by type (A -> front of perm, B -> back) and
// accumulate per-molecule atom counts. Order within a type is irrelevant:
// everything downstream ends in a commutative segment-sum.
// ---------------------------------------------------------------------------
__global__ void partition_kernel(const int* __restrict__ types,
                                 const int* __restrict__ mol_id,
                                 int* __restrict__ ws) {
    int i = blockIdx.x * blockDim.x + threadIdx.x;
    if (i >= N_ATOMS) return;
    int* cnt  = ws + WS_CNT;
    int* perm = ws + WS_PERM;
    if (types[i] == 0) {
        int p = atomicAdd(&cnt[0], 1);
        perm[p] = i;
    } else {
        int p = atomicAdd(&cnt[1], 1);
        perm[N_ATOMS - 1 - p] = i;
    }
    float* mol_cnt = (float*)ws + WS_MOLCNT;
    atomicAdd(&mol_cnt[mol_id[i]], 1.0f);
}

// ---------------------------------------------------------------------------
// Kernel 2: fused per-type MLP. Grid = 2*NB_SIDE blocks; blocks [0,NB_SIDE)
// take type-A rows from the front of perm, blocks [NB_SIDE,..) take type-B
// rows from the back. Blocks past the runtime partition size exit early.
// Each block: 32 atoms, 256 threads, 8x8 register micro-tile per thread.
// Layer3 fused into layer2 epilogue; one atomicAdd per atom into mol_sum.
// ---------------------------------------------------------------------------
__global__ __launch_bounds__(256, 2)
void mlp_kernel(const float* __restrict__ Gs,
                const int*   __restrict__ mol_id,
                const float* __restrict__ W1A, const float* __restrict__ b1A,
                const float* __restrict__ W2A, const float* __restrict__ b2A,
                const float* __restrict__ W3A, const float* __restrict__ b3A,
                const float* __restrict__ offA,
                const float* __restrict__ W1B, const float* __restrict__ b1B,
                const float* __restrict__ W2B, const float* __restrict__ b2B,
                const float* __restrict__ W3B, const float* __restrict__ b3B,
                const float* __restrict__ offB,
                int* __restrict__ ws) {
    __shared__ __align__(16) float sG[BM][NUM_GS];   // 16 KB
    __shared__ __align__(16) float sH[BM][HIDDEN];   // 64 KB
    __shared__ int sOrig[BM];

    const int* cnt  = ws + WS_CNT;
    const int* perm = ws + WS_PERM;
    float* mol_sum  = (float*)ws + WS_MOLSUM;

    const int b     = blockIdx.x;
    const int nA    = cnt[0];
    const int sideB = (b >= NB_SIDE) ? 1 : 0;
    const int r0    = (sideB ? b - NB_SIDE : b) * BM;
    const int nSide = sideB ? (N_ATOMS - nA) : nA;
    if (r0 >= nSide) return;

    const float *W1, *b1, *W2, *b2, *W3;
    float b3off;
    if (!sideB) { W1 = W1A; b1 = b1A; W2 = W2A; b2 = b2A; W3 = W3A; b3off = b3A[0] + offA[0]; }
    else        { W1 = W1B; b1 = b1B; W2 = W2B; b2 = b2B; W3 = W3B; b3off = b3B[0] + offB[0]; }

    const int tid = threadIdx.x;
    if (tid < BM) {
        int r = r0 + tid;
        int orig = -1;
        if (r < nSide) orig = sideB ? perm[N_ATOMS - 1 - r] : perm[r];
        sOrig[tid] = orig;
    }
    __syncthreads();

    // ---- stage G tile: 32 rows x 128 cols, float4-vectorized, row-gathered
    #pragma unroll
    for (int q = 0; q < 4; ++q) {
        int idx = tid + 256 * q;        // 0..1023 float4 slots
        int row = idx >> 5;             // 32 float4 per row
        int c4  = idx & 31;
        int orig = sOrig[row];
        float4 v = make_float4(0.f, 0.f, 0.f, 0.f);
        if (orig >= 0) v = ((const float4*)(Gs + (size_t)orig * NUM_GS))[c4];
        ((float4*)&sG[row][0])[c4] = v;
    }
    __syncthreads();

    const int tx = tid & 63;            // col lane: j = tx + 64*jj
    const int ty = tid >> 6;            // atom group: a = ty*8 + aa

    float acc[8][8];
    #pragma unroll
    for (int aa = 0; aa < 8; ++aa)
        #pragma unroll
        for (int jj = 0; jj < 8; ++jj) acc[aa][jj] = 0.f;

    // ---- layer 1: h1 = tanh(G @ W1 + b1), K = 128
    for (int k0 = 0; k0 < NUM_GS; k0 += 4) {
        float4 ga[8];
        #pragma unroll
        for (int aa = 0; aa < 8; ++aa)
            ga[aa] = *(const float4*)&sG[ty * 8 + aa][k0];
        #pragma unroll
        for (int kk = 0; kk < 4; ++kk) {
            const float* Wrow = W1 + (size_t)(k0 + kk) * HIDDEN + tx;
            float w[8];
            #pragma unroll
            for (int jj = 0; jj < 8; ++jj) w[jj] = Wrow[64 * jj];
            #pragma unroll
            for (int aa = 0; aa < 8; ++aa) {
                float gk = ((const float*)&ga[aa])[kk];
                #pragma unroll
                for (int jj = 0; jj < 8; ++jj)
                    acc[aa][jj] = fmaf(gk, w[jj], acc[aa][jj]);
            }
        }
    }
    {
        float bb[8];
        #pragma unroll
        for (int jj = 0; jj < 8; ++jj) bb[jj] = b1[tx + 64 * jj];
        #pragma unroll
        for (int aa = 0; aa < 8; ++aa)
            #pragma unroll
            for (int jj = 0; jj < 8; ++jj)
                sH[ty * 8 + aa][tx + 64 * jj] = fast_tanh(acc[aa][jj] + bb[jj]);
    }
    __syncthreads();

    // ---- layer 2: pre2 = h1 @ W2 + b2, K = 512 (h2 never materialized)
    #pragma unroll
    for (int aa = 0; aa < 8; ++aa)
        #pragma unroll
        for (int jj = 0; jj < 8; ++jj) acc[aa][jj] = 0.f;

    for (int k0 = 0; k0 < HIDDEN; k0 += 4) {
        float4 ga[8];
        #pragma unroll
        for (int aa = 0; aa < 8; ++aa)
            ga[aa] = *(const float4*)&sH[ty * 8 + aa][k0];
        #pragma unroll
        for (int kk = 0; kk < 4; ++kk) {
            const float* Wrow = W2 + (size_t)(k0 + kk) * HIDDEN + tx;
            float w[8];
            #pragma unroll
            for (int jj = 0; jj < 8; ++jj) w[jj] = Wrow[64 * jj];
            #pragma unroll
            for (int aa = 0; aa < 8; ++aa) {
                float gk = ((const float*)&ga[aa])[kk];
                #pragma unroll
                for (int jj = 0; jj < 8; ++jj)
                    acc[aa][jj] = fmaf(gk, w[jj], acc[aa][jj]);
            }
        }
    }

    // ---- layer 3 fused: e = sum_j tanh(pre2_j + b2_j) * W3_j  (+ b3 + off)
    float b2v[8], w3v[8];
    #pragma unroll
    for (int jj = 0; jj < 8; ++jj) {
        b2v[jj] = b2[tx + 64 * jj];
        w3v[jj] = W3[tx + 64 * jj];
    }
    float ep[8];
    #pragma unroll
    for (int aa = 0; aa < 8; ++aa) {
        float p = 0.f;
        #pragma unroll
        for (int jj = 0; jj < 8; ++jj)
            p += fast_tanh(acc[aa][jj] + b2v[jj]) * w3v[jj];
        ep[aa] = p;
    }
    // wave(64)-reduce each atom's partial across tx
    #pragma unroll
    for (int aa = 0; aa < 8; ++aa) {
        float p = ep[aa];
        #pragma unroll
        for (int s = 32; s > 0; s >>= 1) p += __shfl_xor(p, s, 64);
        ep[aa] = p;
    }
    if (tx == 0) {
        #pragma unroll
        for (int aa = 0; aa < 8; ++aa) {
            int a = ty * 8 + aa;
            int orig = sOrig[a];
            if (orig >= 0) {
                float e = ep[aa] + b3off;
                atomicAdd(&mol_sum[mol_id[orig]], e);
            }
        }
    }
}

// ---------------------------------------------------------------------------
// Kernel 3: per-molecule mean
// ---------------------------------------------------------------------------
__global__ void finalize_kernel(const int* __restrict__ ws,
                                float* __restrict__ out) {
    int m = blockIdx.x * blockDim.x + threadIdx.x;
    if (m >= N_MOL) return;
    const float* mol_sum = (const float*)ws + WS_MOLSUM;
    const float* mol_cnt = (const float*)ws + WS_MOLCNT;
    out[m] = mol_sum[m] / fmaxf(mol_cnt[m], 1.0f);
}

extern "C" void kernel_launch(void* const* d_in, const int* in_sizes, int n_in,
                              void* d_out, int out_size, void* d_ws, size_t ws_size,
                              hipStream_t stream) {
    const float* Gs     = (const float*)d_in[0];
    const int*   types  = (const int*)d_in[1];
    const int*   mol_id = (const int*)d_in[2];
    const float* W1A = (const float*)d_in[3];
    const float* b1A = (const float*)d_in[4];
    const float* W2A = (const float*)d_in[5];
    const float* b2A = (const float*)d_in[6];
    const float* W3A = (const float*)d_in[7];
    const float* b3A = (const float*)d_in[8];
    const float* oA  = (const float*)d_in[9];
    const float* W1B = (const float*)d_in[10];
    const float* b1B = (const float*)d_in[11];
    const float* W2B = (const float*)d_in[12];
    const float* b2B = (const float*)d_in[13];
    const float* W3B = (const float*)d_in[14];
    const float* b3B = (const float*)d_in[15];
    const float* oB  = (const float*)d_in[16];

    int* ws = (int*)d_ws;
    float* out = (float*)d_out;

    hipMemsetAsync(d_ws, 0, WS_ZERO_BYTES, stream);
    partition_kernel<<<N_ATOMS / 256, 256, 0, stream>>>(types, mol_id, ws);
    mlp_kernel<<<2 * NB_SIDE, 256, 0, stream>>>(
        Gs, mol_id,
        W1A, b1A, W2A, b2A, W3A, b3A, oA,
        W1B, b1B, W2B, b2B, W3B, b3B, oB,
        ws);
    finalize_kernel<<<(N_MOL + 255) / 256, 256, 0, stream>>>(ws, out);
}

// Round 2
// 1365.259 us; speedup vs baseline: 1.1849x; 1.1849x over previous
//
#include <hip/hip_runtime.h>

#define N_ATOMS 131072
#define NUM_GS  128
#define HIDDEN  512
#define N_MOL   1024

#define BM      32                      // atoms per MLP block
#define NB_SIDE (N_ATOMS / BM)          // 4096 blocks per type-side
#define HCHUNK  256                     // sH column chunk (2 passes over HIDDEN)

// ---- workspace layout (in 4-byte elements) ----
#define WS_CNT        0
#define WS_MOLSUM     16
#define WS_MOLCNT     1040
#define WS_PERM       2064
#define WS_ZERO_BYTES (2064 * 4)

__device__ __forceinline__ float fast_tanh(float x) {
    x = fminf(20.f, fmaxf(-20.f, x));
    float e = __expf(2.f * x);
    return (e - 1.f) / (e + 1.f);
}

// ---------------------------------------------------------------------------
// Kernel 1: partition atoms by type; accumulate per-molecule counts.
// ---------------------------------------------------------------------------
__global__ void partition_kernel(const int* __restrict__ types,
                                 const int* __restrict__ mol_id,
                                 int* __restrict__ ws) {
    int i = blockIdx.x * blockDim.x + threadIdx.x;
    if (i >= N_ATOMS) return;
    int* cnt  = ws + WS_CNT;
    int* perm = ws + WS_PERM;
    if (types[i] == 0) {
        int p = atomicAdd(&cnt[0], 1);
        perm[p] = i;
    } else {
        int p = atomicAdd(&cnt[1], 1);
        perm[N_ATOMS - 1 - p] = i;
    }
    float* mol_cnt = (float*)ws + WS_MOLCNT;
    atomicAdd(&mol_cnt[mol_id[i]], 1.0f);
}

// ---------------------------------------------------------------------------
// Kernel 2: fused per-type MLP, chunked-sH variant.
// LDS = sG 16KB + sH 32KB -> ~49.3 KB -> 3 blocks/CU (was 82KB -> 1 block/CU).
// HIDDEN processed in two 256-col chunks: layer1 chunk -> sH -> layer2 K-chunk.
// acc2[8][8] (layer-2 pre-activations) persists across chunks.
// ---------------------------------------------------------------------------
__global__ __launch_bounds__(256, 3)
void mlp_kernel(const float* __restrict__ Gs,
                const int*   __restrict__ mol_id,
                const float* __restrict__ W1A, const float* __restrict__ b1A,
                const float* __restrict__ W2A, const float* __restrict__ b2A,
                const float* __restrict__ W3A, const float* __restrict__ b3A,
                const float* __restrict__ offA,
                const float* __restrict__ W1B, const float* __restrict__ b1B,
                const float* __restrict__ W2B, const float* __restrict__ b2B,
                const float* __restrict__ W3B, const float* __restrict__ b3B,
                const float* __restrict__ offB,
                int* __restrict__ ws) {
    __shared__ __align__(16) float sG[BM][NUM_GS];   // 16 KB
    __shared__ __align__(16) float sH[BM][HCHUNK];   // 32 KB
    __shared__ int sOrig[BM];

    const int* cnt  = ws + WS_CNT;
    const int* perm = ws + WS_PERM;
    float* mol_sum  = (float*)ws + WS_MOLSUM;

    const int b     = blockIdx.x;
    const int nA    = cnt[0];
    const int sideB = (b >= NB_SIDE) ? 1 : 0;
    const int r0    = (sideB ? b - NB_SIDE : b) * BM;
    const int nSide = sideB ? (N_ATOMS - nA) : nA;
    if (r0 >= nSide) return;

    const float *W1, *b1, *W2, *b2, *W3;
    float b3off;
    if (!sideB) { W1 = W1A; b1 = b1A; W2 = W2A; b2 = b2A; W3 = W3A; b3off = b3A[0] + offA[0]; }
    else        { W1 = W1B; b1 = b1B; W2 = W2B; b2 = b2B; W3 = W3B; b3off = b3B[0] + offB[0]; }

    const int tid = threadIdx.x;
    if (tid < BM) {
        int r = r0 + tid;
        int orig = -1;
        if (r < nSide) orig = sideB ? perm[N_ATOMS - 1 - r] : perm[r];
        sOrig[tid] = orig;
    }
    __syncthreads();

    // ---- stage G tile: 32 rows x 128 cols, float4-vectorized, row-gathered
    #pragma unroll
    for (int q = 0; q < 4; ++q) {
        int idx = tid + 256 * q;        // 0..1023 float4 slots
        int row = idx >> 5;             // 32 float4 per row
        int c4  = idx & 31;
        int orig = sOrig[row];
        float4 v = make_float4(0.f, 0.f, 0.f, 0.f);
        if (orig >= 0) v = ((const float4*)(Gs + (size_t)orig * NUM_GS))[c4];
        ((float4*)&sG[row][0])[c4] = v;
    }
    __syncthreads();

    const int tx = tid & 63;            // col lane: j = tx + 64*jj
    const int ty = tid >> 6;            // atom group: a = ty*8 + aa

    float acc2[8][8];                   // layer-2 pre-activations, full 512 cols
    #pragma unroll
    for (int aa = 0; aa < 8; ++aa)
        #pragma unroll
        for (int jj = 0; jj < 8; ++jj) acc2[aa][jj] = 0.f;

    for (int c = 0; c < 2; ++c) {
        const int cbase = c * HCHUNK;

        // ---- layer 1 chunk: h1[:, cbase..cbase+255] = tanh(G @ W1 + b1)
        float acc1[8][4];
        #pragma unroll
        for (int aa = 0; aa < 8; ++aa)
            #pragma unroll
            for (int jj = 0; jj < 4; ++jj) acc1[aa][jj] = 0.f;

        for (int k0 = 0; k0 < NUM_GS; k0 += 4) {
            float4 ga[8];
            #pragma unroll
            for (int aa = 0; aa < 8; ++aa)
                ga[aa] = *(const float4*)&sG[ty * 8 + aa][k0];
            #pragma unroll
            for (int kk = 0; kk < 4; ++kk) {
                const float* Wrow = W1 + (size_t)(k0 + kk) * HIDDEN + cbase + tx;
                float w[4];
                #pragma unroll
                for (int jj = 0; jj < 4; ++jj) w[jj] = Wrow[64 * jj];
                #pragma unroll
                for (int aa = 0; aa < 8; ++aa) {
                    float gk = ((const float*)&ga[aa])[kk];
                    #pragma unroll
                    for (int jj = 0; jj < 4; ++jj)
                        acc1[aa][jj] = fmaf(gk, w[jj], acc1[aa][jj]);
                }
            }
        }
        {
            float bb[4];
            #pragma unroll
            for (int jj = 0; jj < 4; ++jj) bb[jj] = b1[cbase + tx + 64 * jj];
            #pragma unroll
            for (int aa = 0; aa < 8; ++aa)
                #pragma unroll
                for (int jj = 0; jj < 4; ++jj)
                    sH[ty * 8 + aa][tx + 64 * jj] = fast_tanh(acc1[aa][jj] + bb[jj]);
        }
        __syncthreads();

        // ---- layer 2 partial: acc2 += h1_chunk @ W2[cbase..cbase+255, :]
        for (int k0 = 0; k0 < HCHUNK; k0 += 4) {
            float4 ga[8];
            #pragma unroll
            for (int aa = 0; aa < 8; ++aa)
                ga[aa] = *(const float4*)&sH[ty * 8 + aa][k0];
            #pragma unroll
            for (int kk = 0; kk < 4; ++kk) {
                const float* Wrow = W2 + (size_t)(cbase + k0 + kk) * HIDDEN + tx;
                float w[8];
                #pragma unroll
                for (int jj = 0; jj < 8; ++jj) w[jj] = Wrow[64 * jj];
                #pragma unroll
                for (int aa = 0; aa < 8; ++aa) {
                    float gk = ((const float*)&ga[aa])[kk];
                    #pragma unroll
                    for (int jj = 0; jj < 8; ++jj)
                        acc2[aa][jj] = fmaf(gk, w[jj], acc2[aa][jj]);
                }
            }
        }
        __syncthreads();   // protect sH before next chunk overwrites it
    }

    // ---- layer 3 fused: e = sum_j tanh(acc2_j + b2_j) * W3_j  (+ b3 + off)
    float b2v[8], w3v[8];
    #pragma unroll
    for (int jj = 0; jj < 8; ++jj) {
        b2v[jj] = b2[tx + 64 * jj];
        w3v[jj] = W3[tx + 64 * jj];
    }
    float ep[8];
    #pragma unroll
    for (int aa = 0; aa < 8; ++aa) {
        float p = 0.f;
        #pragma unroll
        for (int jj = 0; jj < 8; ++jj)
            p += fast_tanh(acc2[aa][jj] + b2v[jj]) * w3v[jj];
        ep[aa] = p;
    }
    #pragma unroll
    for (int aa = 0; aa < 8; ++aa) {
        float p = ep[aa];
        #pragma unroll
        for (int s = 32; s > 0; s >>= 1) p += __shfl_xor(p, s, 64);
        ep[aa] = p;
    }
    if (tx == 0) {
        #pragma unroll
        for (int aa = 0; aa < 8; ++aa) {
            int a = ty * 8 + aa;
            int orig = sOrig[a];
            if (orig >= 0) {
                float e = ep[aa] + b3off;
                atomicAdd(&mol_sum[mol_id[orig]], e);
            }
        }
    }
}

// ---------------------------------------------------------------------------
// Kernel 3: per-molecule mean
// ---------------------------------------------------------------------------
__global__ void finalize_kernel(const int* __restrict__ ws,
                                float* __restrict__ out) {
    int m = blockIdx.x * blockDim.x + threadIdx.x;
    if (m >= N_MOL) return;
    const float* mol_sum = (const float*)ws + WS_MOLSUM;
    const float* mol_cnt = (const float*)ws + WS_MOLCNT;
    out[m] = mol_sum[m] / fmaxf(mol_cnt[m], 1.0f);
}

extern "C" void kernel_launch(void* const* d_in, const int* in_sizes, int n_in,
                              void* d_out, int out_size, void* d_ws, size_t ws_size,
                              hipStream_t stream) {
    const float* Gs     = (const float*)d_in[0];
    const int*   types  = (const int*)d_in[1];
    const int*   mol_id = (const int*)d_in[2];
    const float* W1A = (const float*)d_in[3];
    const float* b1A = (const float*)d_in[4];
    const float* W2A = (const float*)d_in[5];
    const float* b2A = (const float*)d_in[6];
    const float* W3A = (const float*)d_in[7];
    const float* b3A = (const float*)d_in[8];
    const float* oA  = (const float*)d_in[9];
    const float* W1B = (const float*)d_in[10];
    const float* b1B = (const float*)d_in[11];
    const float* W2B = (const float*)d_in[12];
    const float* b2B = (const float*)d_in[13];
    const float* W3B = (const float*)d_in[14];
    const float* b3B = (const float*)d_in[15];
    const float* oB  = (const float*)d_in[16];

    int* ws = (int*)d_ws;
    float* out = (float*)d_out;

    hipMemsetAsync(d_ws, 0, WS_ZERO_BYTES, stream);
    partition_kernel<<<N_ATOMS / 256, 256, 0, stream>>>(types, mol_id, ws);
    mlp_kernel<<<2 * NB_SIDE, 256, 0, stream>>>(
        Gs, mol_id,
        W1A, b1A, W2A, b2A, W3A, b3A, oA,
        W1B, b1B, W2B, b2B, W3B, b3B, oB,
        ws);
    finalize_kernel<<<(N_MOL + 255) / 256, 256, 0, stream>>>(ws, out);
}

// Round 3
// 566.850 us; speedup vs baseline: 2.8537x; 2.4085x over previous
//
#include <hip/hip_runtime.h>

typedef _Float16 half8  __attribute__((ext_vector_type(8)));
typedef _Float16 half4  __attribute__((ext_vector_type(4)));
typedef float    floatx4 __attribute__((ext_vector_type(4)));

#define N_ATOMS 131072
#define NUM_GS  128
#define HIDDEN  512
#define N_MOL   1024

#define BM      32                      // atoms per MLP block
#define NB_SIDE (N_ATOMS / BM)          // 4096 blocks per type-side

// ---- workspace byte offsets ----
#define WS_CNT_OFF     0               // int[2]
#define WS_MOLSUM_OFF  1024            // float[1024]
#define WS_MOLCNT_OFF  5120            // float[1024]
#define WS_PERM_OFF    9216            // int[131072]
#define WS_W1TA_OFF    533504          // fp16[512*128]
#define WS_W1TB_OFF    664576
#define WS_W2TA_OFF    795648          // fp16[512*512]
#define WS_W2TB_OFF    1319936
#define WS_ZERO_BYTES  9216

__device__ __forceinline__ float fast_tanh(float x) {
    x = fminf(20.f, fmaxf(-20.f, x));
    float e = __expf(2.f * x);
    return (e - 1.f) / (e + 1.f);
}

// ---------------------------------------------------------------------------
// Kernel 1: partition atoms by type; accumulate per-molecule counts.
// ---------------------------------------------------------------------------
__global__ void partition_kernel(const int* __restrict__ types,
                                 const int* __restrict__ mol_id,
                                 int* __restrict__ cnt,
                                 int* __restrict__ perm,
                                 float* __restrict__ mol_cnt) {
    int i = blockIdx.x * blockDim.x + threadIdx.x;
    if (i >= N_ATOMS) return;
    if (types[i] == 0) {
        int p = atomicAdd(&cnt[0], 1);
        perm[p] = i;
    } else {
        int p = atomicAdd(&cnt[1], 1);
        perm[N_ATOMS - 1 - p] = i;
    }
    atomicAdd(&mol_cnt[mol_id[i]], 1.0f);
}

// ---------------------------------------------------------------------------
// Kernel 2: fp32 [K][N] -> fp16 [N][K] tiled transpose (coalesced both sides).
// Launch: grid (N/32, K/32), block (32, 8).
// ---------------------------------------------------------------------------
__global__ void cvt_transpose_kernel(const float* __restrict__ in,
                                     _Float16* __restrict__ out,
                                     int K, int N) {
    __shared__ float tile[32][33];
    const int n0 = blockIdx.x * 32;
    const int k0 = blockIdx.y * 32;
    for (int i = threadIdx.y; i < 32; i += 8)
        tile[i][threadIdx.x] = in[(size_t)(k0 + i) * N + n0 + threadIdx.x];
    __syncthreads();
    for (int i = threadIdx.y; i < 32; i += 8)
        out[(size_t)(n0 + i) * K + k0 + threadIdx.x] = (_Float16)tile[threadIdx.x][i];
}

// ---------------------------------------------------------------------------
// Kernel 3: fused per-type MLP with f16 MFMA (fp32 accumulate).
// Block = 32 atoms, 256 threads (4 waves); wave w owns cols [128w,128w+128).
// Fragment layouts (gfx950 16x16x32, HW-verified m89/m120):
//   A: m = lane&15, k = (lane>>4)*8 + j     (8 f16, 16B contiguous)
//   B: n = lane&15, k = (lane>>4)*8 + j     (-> needs W^T[n][k] in memory)
//   C/D: col = lane&15, row = (lane>>4)*4 + reg
// LDS = sGh 8.5K + sH1 32.5K + misc -> 42.6 KB -> 3 blocks/CU.
// ---------------------------------------------------------------------------
__global__ __launch_bounds__(256, 3)
void mlp_kernel(const float* __restrict__ Gs,
                const int*   __restrict__ mol_id,
                const _Float16* __restrict__ W1TA, const _Float16* __restrict__ W2TA,
                const float* __restrict__ b1A, const float* __restrict__ b2A,
                const float* __restrict__ W3A, const float* __restrict__ b3A,
                const float* __restrict__ offA,
                const _Float16* __restrict__ W1TB, const _Float16* __restrict__ W2TB,
                const float* __restrict__ b1B, const float* __restrict__ b2B,
                const float* __restrict__ W3B, const float* __restrict__ b3B,
                const float* __restrict__ offB,
                const int* __restrict__ cnt, const int* __restrict__ perm,
                float* __restrict__ mol_sum) {
    __shared__ __align__(16) _Float16 sGh[BM][NUM_GS + 8];   // +8 pad: 2-way alias (free)
    __shared__ __align__(16) _Float16 sH1[BM][HIDDEN + 8];
    __shared__ int   sOrig[BM];
    __shared__ float sPart[4][BM];

    const int b     = blockIdx.x;
    const int nA    = cnt[0];
    const int sideB = (b >= NB_SIDE) ? 1 : 0;
    const int r0    = (sideB ? b - NB_SIDE : b) * BM;
    const int nSide = sideB ? (N_ATOMS - nA) : nA;
    if (r0 >= nSide) return;

    const _Float16 *W1T, *W2T;
    const float *b1, *b2, *W3;
    float b3off;
    if (!sideB) { W1T = W1TA; W2T = W2TA; b1 = b1A; b2 = b2A; W3 = W3A; b3off = b3A[0] + offA[0]; }
    else        { W1T = W1TB; W2T = W2TB; b1 = b1B; b2 = b2B; W3 = W3B; b3off = b3B[0] + offB[0]; }

    const int tid = threadIdx.x;
    if (tid < BM) {
        int r = r0 + tid;
        int orig = -1;
        if (r < nSide) orig = sideB ? perm[N_ATOMS - 1 - r] : perm[r];
        sOrig[tid] = orig;
    }
    __syncthreads();

    // ---- stage G tile (fp32 -> fp16): 32 rows x 128 cols
    #pragma unroll
    for (int q = 0; q < 4; ++q) {
        int idx = tid + 256 * q;        // 0..1023 float4 slots
        int row = idx >> 5;             // 32 float4 per row
        int c4  = idx & 31;
        int orig = sOrig[row];
        float4 v = make_float4(0.f, 0.f, 0.f, 0.f);
        if (orig >= 0) v = ((const float4*)(Gs + (size_t)orig * NUM_GS))[c4];
        half4 h; h[0] = (_Float16)v.x; h[1] = (_Float16)v.y;
                 h[2] = (_Float16)v.z; h[3] = (_Float16)v.w;
        *(half4*)&sGh[row][c4 * 4] = h;
    }
    __syncthreads();

    const int lane = tid & 63;
    const int wid  = tid >> 6;          // wave id: cols [128*wid, 128*wid+128)
    const int l15  = lane & 15;
    const int quad = lane >> 4;
    const int colBase = wid * 128 + l15;

    // ================= layer 1: H1 = tanh(G @ W1 + b1) =================
    floatx4 acc[2][8];
    #pragma unroll
    for (int mt = 0; mt < 2; ++mt)
        #pragma unroll
        for (int nt = 0; nt < 8; ++nt) acc[mt][nt] = (floatx4){0.f, 0.f, 0.f, 0.f};

    #pragma unroll 2
    for (int ks = 0; ks < NUM_GS / 32; ++ks) {
        half8 a0 = *(const half8*)&sGh[l15][ks * 32 + quad * 8];
        half8 a1 = *(const half8*)&sGh[l15 + 16][ks * 32 + quad * 8];
        #pragma unroll
        for (int nt = 0; nt < 8; ++nt) {
            int n = colBase + nt * 16;
            half8 bfr = *(const half8*)(W1T + (size_t)n * NUM_GS + ks * 32 + quad * 8);
            acc[0][nt] = __builtin_amdgcn_mfma_f32_16x16x32_f16(a0, bfr, acc[0][nt], 0, 0, 0);
            acc[1][nt] = __builtin_amdgcn_mfma_f32_16x16x32_f16(a1, bfr, acc[1][nt], 0, 0, 0);
        }
    }
    // epilogue: tanh -> sH1 (fp16, A-layout for layer 2)
    #pragma unroll
    for (int nt = 0; nt < 8; ++nt) {
        int col = colBase + nt * 16;
        float b1v = b1[col];
        #pragma unroll
        for (int mt = 0; mt < 2; ++mt)
            #pragma unroll
            for (int r = 0; r < 4; ++r) {
                int row = mt * 16 + quad * 4 + r;
                sH1[row][col] = (_Float16)fast_tanh(acc[mt][nt][r] + b1v);
            }
    }
    __syncthreads();

    // ================= layer 2: pre2 = H1 @ W2 + b2 =================
    #pragma unroll
    for (int mt = 0; mt < 2; ++mt)
        #pragma unroll
        for (int nt = 0; nt < 8; ++nt) acc[mt][nt] = (floatx4){0.f, 0.f, 0.f, 0.f};

    #pragma unroll 2
    for (int ks = 0; ks < HIDDEN / 32; ++ks) {
        half8 a0 = *(const half8*)&sH1[l15][ks * 32 + quad * 8];
        half8 a1 = *(const half8*)&sH1[l15 + 16][ks * 32 + quad * 8];
        #pragma unroll
        for (int nt = 0; nt < 8; ++nt) {
            int n = colBase + nt * 16;
            half8 bfr = *(const half8*)(W2T + (size_t)n * HIDDEN + ks * 32 + quad * 8);
            acc[0][nt] = __builtin_amdgcn_mfma_f32_16x16x32_f16(a0, bfr, acc[0][nt], 0, 0, 0);
            acc[1][nt] = __builtin_amdgcn_mfma_f32_16x16x32_f16(a1, bfr, acc[1][nt], 0, 0, 0);
        }
    }

    // ======== layer 3 fused: e = sum_j tanh(pre2_j)*W3_j + b3 + off ========
    float p[2][4];
    #pragma unroll
    for (int mt = 0; mt < 2; ++mt)
        #pragma unroll
        for (int r = 0; r < 4; ++r) p[mt][r] = 0.f;

    #pragma unroll
    for (int nt = 0; nt < 8; ++nt) {
        int col = colBase + nt * 16;
        float b2v = b2[col];
        float w3v = W3[col];
        #pragma unroll
        for (int mt = 0; mt < 2; ++mt)
            #pragma unroll
            for (int r = 0; r < 4; ++r)
                p[mt][r] += fast_tanh(acc[mt][nt][r] + b2v) * w3v;
    }
    // reduce over the 16 cols held across lanes sharing a quad (xor low 4 bits)
    #pragma unroll
    for (int mt = 0; mt < 2; ++mt)
        #pragma unroll
        for (int r = 0; r < 4; ++r) {
            float v = p[mt][r];
            v += __shfl_xor(v, 1, 64);
            v += __shfl_xor(v, 2, 64);
            v += __shfl_xor(v, 4, 64);
            v += __shfl_xor(v, 8, 64);
            p[mt][r] = v;
        }
    if (l15 == 0) {
        #pragma unroll
        for (int mt = 0; mt < 2; ++mt)
            #pragma unroll
            for (int r = 0; r < 4; ++r)
                sPart[wid][mt * 16 + quad * 4 + r] = p[mt][r];
    }
    __syncthreads();
    if (tid < BM) {
        int orig = sOrig[tid];
        if (orig >= 0) {
            float e = sPart[0][tid] + sPart[1][tid] + sPart[2][tid] + sPart[3][tid] + b3off;
            atomicAdd(&mol_sum[mol_id[orig]], e);
        }
    }
}

// ---------------------------------------------------------------------------
// Kernel 4: per-molecule mean
// ---------------------------------------------------------------------------
__global__ void finalize_kernel(const float* __restrict__ mol_sum,
                                const float* __restrict__ mol_cnt,
                                float* __restrict__ out) {
    int m = blockIdx.x * blockDim.x + threadIdx.x;
    if (m >= N_MOL) return;
    out[m] = mol_sum[m] / fmaxf(mol_cnt[m], 1.0f);
}

extern "C" void kernel_launch(void* const* d_in, const int* in_sizes, int n_in,
                              void* d_out, int out_size, void* d_ws, size_t ws_size,
                              hipStream_t stream) {
    const float* Gs     = (const float*)d_in[0];
    const int*   types  = (const int*)d_in[1];
    const int*   mol_id = (const int*)d_in[2];
    const float* W1A = (const float*)d_in[3];
    const float* b1A = (const float*)d_in[4];
    const float* W2A = (const float*)d_in[5];
    const float* b2A = (const float*)d_in[6];
    const float* W3A = (const float*)d_in[7];
    const float* b3A = (const float*)d_in[8];
    const float* oA  = (const float*)d_in[9];
    const float* W1B = (const float*)d_in[10];
    const float* b1B = (const float*)d_in[11];
    const float* W2B = (const float*)d_in[12];
    const float* b2B = (const float*)d_in[13];
    const float* W3B = (const float*)d_in[14];
    const float* b3B = (const float*)d_in[15];
    const float* oB  = (const float*)d_in[16];

    char* ws = (char*)d_ws;
    int*      cnt     = (int*)(ws + WS_CNT_OFF);
    float*    mol_sum = (float*)(ws + WS_MOLSUM_OFF);
    float*    mol_cnt = (float*)(ws + WS_MOLCNT_OFF);
    int*      perm    = (int*)(ws + WS_PERM_OFF);
    _Float16* W1TA    = (_Float16*)(ws + WS_W1TA_OFF);
    _Float16* W1TB    = (_Float16*)(ws + WS_W1TB_OFF);
    _Float16* W2TA    = (_Float16*)(ws + WS_W2TA_OFF);
    _Float16* W2TB    = (_Float16*)(ws + WS_W2TB_OFF);
    float* out = (float*)d_out;

    hipMemsetAsync(d_ws, 0, WS_ZERO_BYTES, stream);
    partition_kernel<<<N_ATOMS / 256, 256, 0, stream>>>(types, mol_id, cnt, perm, mol_cnt);

    dim3 tb(32, 8);
    cvt_transpose_kernel<<<dim3(HIDDEN / 32, NUM_GS / 32), tb, 0, stream>>>(W1A, W1TA, NUM_GS, HIDDEN);
    cvt_transpose_kernel<<<dim3(HIDDEN / 32, NUM_GS / 32), tb, 0, stream>>>(W1B, W1TB, NUM_GS, HIDDEN);
    cvt_transpose_kernel<<<dim3(HIDDEN / 32, HIDDEN / 32), tb, 0, stream>>>(W2A, W2TA, HIDDEN, HIDDEN);
    cvt_transpose_kernel<<<dim3(HIDDEN / 32, HIDDEN / 32), tb, 0, stream>>>(W2B, W2TB, HIDDEN, HIDDEN);

    mlp_kernel<<<2 * NB_SIDE, 256, 0, stream>>>(
        Gs, mol_id,
        W1TA, W2TA, b1A, b2A, W3A, b3A, oA,
        W1TB, W2TB, b1B, b2B, W3B, b3B, oB,
        cnt, perm, mol_sum);

    finalize_kernel<<<(N_MOL + 255) / 256, 256, 0, stream>>>(mol_sum, mol_cnt, out);
}

// Round 4
// 495.401 us; speedup vs baseline: 3.2653x; 1.1442x over previous
//
#include <hip/hip_runtime.h>

typedef _Float16 half8  __attribute__((ext_vector_type(8)));
typedef _Float16 half4  __attribute__((ext_vector_type(4)));
typedef float    floatx4 __attribute__((ext_vector_type(4)));

#define N_ATOMS 131072
#define NUM_GS  128
#define HIDDEN  512
#define N_MOL   1024

#define BM      64                      // atoms per MLP block
#define NB_SIDE (N_ATOMS / BM)          // 2048 blocks per type-side
#define HCHUNK  128                     // sH1 column / layer-2 K chunk
#define NCHUNKS (HIDDEN / HCHUNK)       // 4
#define NT_TOT  (HIDDEN / 16)           // 32 n-tiles in fragment layout

// ---- workspace byte offsets ----
#define WS_CNT_OFF     0               // int[2]
#define WS_MOLSUM_OFF  1024            // float[1024]
#define WS_MOLCNT_OFF  5120            // float[1024]
#define WS_PERM_OFF    9216            // int[131072]
#define WS_W1FA_OFF    533504          // fp16 frags 512*128
#define WS_W1FB_OFF    664576
#define WS_W2FA_OFF    795648          // fp16 frags 512*512
#define WS_W2FB_OFF    1319936
#define WS_ZERO_BYTES  9216

__device__ __forceinline__ float fast_tanh(float x) {
    x = fminf(20.f, fmaxf(-20.f, x));
    float e = __expf(2.f * x);
    return (e - 1.f) / (e + 1.f);
}

// ---------------------------------------------------------------------------
// Fused prep kernel (one dispatch):
//  blocks [0,512)    : partition atoms by type + per-molecule counts
//  blocks [512,832)  : pack W1A/W1B/W2A/W2B fp32 [K][N=512] into fp16 MFMA
//                      B-fragment layout [ktile][ntile][lane][8] so that mlp's
//                      B-loads are single fully-coalesced 1KB dwordx4 per wave.
//                      Fragment element: n = ntile*16 + (lane&15),
//                                        k = ktile*32 + (lane>>4)*8 + j.
// ---------------------------------------------------------------------------
__global__ __launch_bounds__(256)
void prep_kernel(const int* __restrict__ types,
                 const int* __restrict__ mol_id,
                 const float* __restrict__ W1A, const float* __restrict__ W1B,
                 const float* __restrict__ W2A, const float* __restrict__ W2B,
                 int* __restrict__ cnt, int* __restrict__ perm,
                 float* __restrict__ mol_cnt,
                 _Float16* __restrict__ W1FA, _Float16* __restrict__ W1FB,
                 _Float16* __restrict__ W2FA, _Float16* __restrict__ W2FB) {
    __shared__ float tile[32][65];
    const int p   = blockIdx.x;
    const int tid = threadIdx.x;

    if (p < 512) {                      // ---- partition ----
        int i = p * 256 + tid;
        if (types[i] == 0) {
            int q = atomicAdd(&cnt[0], 1);
            perm[q] = i;
        } else {
            int q = atomicAdd(&cnt[1], 1);
            perm[N_ATOMS - 1 - q] = i;
        }
        atomicAdd(&mol_cnt[mol_id[i]], 1.0f);
        return;
    }

    // ---- weight pack: block handles K=32 x N=64 region ----
    const float* src; _Float16* dst; int pb;
    if (p < 544)      { src = W1A; dst = W1FA; pb = p - 512; }
    else if (p < 576) { src = W1B; dst = W1FB; pb = p - 544; }
    else if (p < 704) { src = W2A; dst = W2FA; pb = p - 576; }
    else              { src = W2B; dst = W2FB; pb = p - 704; }
    const int bx = pb & 7;              // n-block (8 per row of 512)
    const int by = pb >> 3;             // ktile
    const int n0 = bx * 64, k0 = by * 32;
    #pragma unroll
    for (int i = 0; i < 8; ++i) {
        int idx = tid + i * 256;
        int r = idx >> 6, c = idx & 63;
        tile[r][c] = src[(size_t)(k0 + r) * HIDDEN + n0 + c];
    }
    __syncthreads();
    const int nt_l = tid >> 6, lane = tid & 63;
    const int l15 = lane & 15, q = lane >> 4;
    half8 v;
    #pragma unroll
    for (int j = 0; j < 8; ++j)
        v[j] = (_Float16)tile[q * 8 + j][nt_l * 16 + l15];
    const int ntile = bx * 4 + nt_l;
    *(half8*)(dst + (((size_t)by * NT_TOT + ntile) * 64 + lane) * 8) = v;
}

// ---------------------------------------------------------------------------
// Fused per-type MLP, f16 MFMA, BM=64 atoms/block, 4 waves.
// Layer2: wave w owns cols [128w,128w+128): 4 M-tiles x 8 N-tiles, acc2[4][8].
// Layer1/sH1 processed in 4 chunks of 128 cols (wave owns 32 cols per chunk)
// so LDS stays ~36 KB. B-fragments are lane-linear (packed) -> coalesced.
// ---------------------------------------------------------------------------
__global__ __launch_bounds__(256, 2)
void mlp_kernel(const float* __restrict__ Gs,
                const int*   __restrict__ mol_id,
                const _Float16* __restrict__ W1FA, const _Float16* __restrict__ W2FA,
                const float* __restrict__ b1A, const float* __restrict__ b2A,
                const float* __restrict__ W3A, const float* __restrict__ b3A,
                const float* __restrict__ offA,
                const _Float16* __restrict__ W1FB, const _Float16* __restrict__ W2FB,
                const float* __restrict__ b1B, const float* __restrict__ b2B,
                const float* __restrict__ W3B, const float* __restrict__ b3B,
                const float* __restrict__ offB,
                const int* __restrict__ cnt, const int* __restrict__ perm,
                float* __restrict__ mol_sum) {
    __shared__ __align__(16) _Float16 sGh[BM][NUM_GS + 8];   // 17 KB
    __shared__ __align__(16) _Float16 sH1[BM][HCHUNK + 8];   // 17 KB
    __shared__ int   sOrig[BM];
    __shared__ float sPart[4][BM];

    const int b     = blockIdx.x;
    const int nA    = cnt[0];
    const int sideB = (b >= NB_SIDE) ? 1 : 0;
    const int r0    = (sideB ? b - NB_SIDE : b) * BM;
    const int nSide = sideB ? (N_ATOMS - nA) : nA;
    if (r0 >= nSide) return;

    const _Float16 *W1F, *W2F;
    const float *b1, *b2, *W3;
    float b3off;
    if (!sideB) { W1F = W1FA; W2F = W2FA; b1 = b1A; b2 = b2A; W3 = W3A; b3off = b3A[0] + offA[0]; }
    else        { W1F = W1FB; W2F = W2FB; b1 = b1B; b2 = b2B; W3 = W3B; b3off = b3B[0] + offB[0]; }

    const int tid = threadIdx.x;
    if (tid < BM) {
        int r = r0 + tid;
        int orig = -1;
        if (r < nSide) orig = sideB ? perm[N_ATOMS - 1 - r] : perm[r];
        sOrig[tid] = orig;
    }
    __syncthreads();

    // ---- stage G tile (fp32 -> fp16): 64 rows x 128 cols = 2048 float4
    #pragma unroll
    for (int i = 0; i < 8; ++i) {
        int idx = tid + 256 * i;
        int row = idx >> 5;             // 32 float4 per row
        int c4  = idx & 31;
        int orig = sOrig[row];
        float4 v = make_float4(0.f, 0.f, 0.f, 0.f);
        if (orig >= 0) v = ((const float4*)(Gs + (size_t)orig * NUM_GS))[c4];
        half4 h; h[0] = (_Float16)v.x; h[1] = (_Float16)v.y;
                 h[2] = (_Float16)v.z; h[3] = (_Float16)v.w;
        *(half4*)&sGh[row][c4 * 4] = h;
    }
    __syncthreads();

    const int lane = tid & 63;
    const int wid  = tid >> 6;
    const int l15  = lane & 15;
    const int quad = lane >> 4;

    floatx4 acc2[4][8];                 // layer-2 pre-activations (all 512 cols)
    #pragma unroll
    for (int mt = 0; mt < 4; ++mt)
        #pragma unroll
        for (int nt = 0; nt < 8; ++nt) acc2[mt][nt] = (floatx4){0.f, 0.f, 0.f, 0.f};

    for (int c = 0; c < NCHUNKS; ++c) {
        // ---- layer 1 chunk: cols [c*128, c*128+128); wave owns 32 cols
        floatx4 acc1[4][2];
        #pragma unroll
        for (int mt = 0; mt < 4; ++mt)
            #pragma unroll
            for (int nt = 0; nt < 2; ++nt) acc1[mt][nt] = (floatx4){0.f, 0.f, 0.f, 0.f};

        #pragma unroll 2
        for (int ks = 0; ks < NUM_GS / 32; ++ks) {
            half8 a[4];
            #pragma unroll
            for (int mt = 0; mt < 4; ++mt)
                a[mt] = *(const half8*)&sGh[l15 + 16 * mt][ks * 32 + quad * 8];
            #pragma unroll
            for (int nt = 0; nt < 2; ++nt) {
                int ntile = c * 8 + wid * 2 + nt;
                half8 bf = *(const half8*)(W1F + (((size_t)ks * NT_TOT + ntile) * 64 + lane) * 8);
                #pragma unroll
                for (int mt = 0; mt < 4; ++mt)
                    acc1[mt][nt] = __builtin_amdgcn_mfma_f32_16x16x32_f16(a[mt], bf, acc1[mt][nt], 0, 0, 0);
            }
        }
        #pragma unroll
        for (int nt = 0; nt < 2; ++nt) {
            int colc = wid * 32 + nt * 16 + l15;        // col within chunk
            float b1v = b1[c * HCHUNK + colc];
            #pragma unroll
            for (int mt = 0; mt < 4; ++mt)
                #pragma unroll
                for (int r = 0; r < 4; ++r)
                    sH1[mt * 16 + quad * 4 + r][colc] = (_Float16)fast_tanh(acc1[mt][nt][r] + b1v);
        }
        __syncthreads();

        // ---- layer 2 partial: K-chunk [c*128, c*128+128)
        #pragma unroll 2
        for (int ks = 0; ks < HCHUNK / 32; ++ks) {
            half8 a[4];
            #pragma unroll
            for (int mt = 0; mt < 4; ++mt)
                a[mt] = *(const half8*)&sH1[l15 + 16 * mt][ks * 32 + quad * 8];
            int kt = c * 4 + ks;
            #pragma unroll
            for (int nt = 0; nt < 8; ++nt) {
                int ntile = wid * 8 + nt;
                half8 bf = *(const half8*)(W2F + (((size_t)kt * NT_TOT + ntile) * 64 + lane) * 8);
                #pragma unroll
                for (int mt = 0; mt < 4; ++mt)
                    acc2[mt][nt] = __builtin_amdgcn_mfma_f32_16x16x32_f16(a[mt], bf, acc2[mt][nt], 0, 0, 0);
            }
        }
        __syncthreads();                // protect sH1 before next chunk
    }

    // ======== layer 3 fused: e = sum_j tanh(pre2_j)*W3_j + b3 + off ========
    float p[4][4];
    #pragma unroll
    for (int mt = 0; mt < 4; ++mt)
        #pragma unroll
        for (int r = 0; r < 4; ++r) p[mt][r] = 0.f;

    #pragma unroll
    for (int nt = 0; nt < 8; ++nt) {
        int col = wid * 128 + nt * 16 + l15;
        float b2v = b2[col];
        float w3v = W3[col];
        #pragma unroll
        for (int mt = 0; mt < 4; ++mt)
            #pragma unroll
            for (int r = 0; r < 4; ++r)
                p[mt][r] += fast_tanh(acc2[mt][nt][r] + b2v) * w3v;
    }
    #pragma unroll
    for (int mt = 0; mt < 4; ++mt)
        #pragma unroll
        for (int r = 0; r < 4; ++r) {
            float v = p[mt][r];
            v += __shfl_xor(v, 1, 64);
            v += __shfl_xor(v, 2, 64);
            v += __shfl_xor(v, 4, 64);
            v += __shfl_xor(v, 8, 64);
            p[mt][r] = v;
        }
    if (l15 == 0) {
        #pragma unroll
        for (int mt = 0; mt < 4; ++mt)
            #pragma unroll
            for (int r = 0; r < 4; ++r)
                sPart[wid][mt * 16 + quad * 4 + r] = p[mt][r];
    }
    __syncthreads();
    if (tid < BM) {
        int orig = sOrig[tid];
        if (orig >= 0) {
            float e = sPart[0][tid] + sPart[1][tid] + sPart[2][tid] + sPart[3][tid] + b3off;
            atomicAdd(&mol_sum[mol_id[orig]], e);
        }
    }
}

// ---------------------------------------------------------------------------
// finalize: per-molecule mean
// ---------------------------------------------------------------------------
__global__ void finalize_kernel(const float* __restrict__ mol_sum,
                                const float* __restrict__ mol_cnt,
                                float* __restrict__ out) {
    int m = blockIdx.x * blockDim.x + threadIdx.x;
    if (m >= N_MOL) return;
    out[m] = mol_sum[m] / fmaxf(mol_cnt[m], 1.0f);
}

extern "C" void kernel_launch(void* const* d_in, const int* in_sizes, int n_in,
                              void* d_out, int out_size, void* d_ws, size_t ws_size,
                              hipStream_t stream) {
    const float* Gs     = (const float*)d_in[0];
    const int*   types  = (const int*)d_in[1];
    const int*   mol_id = (const int*)d_in[2];
    const float* W1A = (const float*)d_in[3];
    const float* b1A = (const float*)d_in[4];
    const float* W2A = (const float*)d_in[5];
    const float* b2A = (const float*)d_in[6];
    const float* W3A = (const float*)d_in[7];
    const float* b3A = (const float*)d_in[8];
    const float* oA  = (const float*)d_in[9];
    const float* W1B = (const float*)d_in[10];
    const float* b1B = (const float*)d_in[11];
    const float* W2B = (const float*)d_in[12];
    const float* b2B = (const float*)d_in[13];
    const float* W3B = (const float*)d_in[14];
    const float* b3B = (const float*)d_in[15];
    const float* oB  = (const float*)d_in[16];

    char* ws = (char*)d_ws;
    int*      cnt     = (int*)(ws + WS_CNT_OFF);
    float*    mol_sum = (float*)(ws + WS_MOLSUM_OFF);
    float*    mol_cnt = (float*)(ws + WS_MOLCNT_OFF);
    int*      perm    = (int*)(ws + WS_PERM_OFF);
    _Float16* W1FA    = (_Float16*)(ws + WS_W1FA_OFF);
    _Float16* W1FB    = (_Float16*)(ws + WS_W1FB_OFF);
    _Float16* W2FA    = (_Float16*)(ws + WS_W2FA_OFF);
    _Float16* W2FB    = (_Float16*)(ws + WS_W2FB_OFF);
    float* out = (float*)d_out;

    hipMemsetAsync(d_ws, 0, WS_ZERO_BYTES, stream);
    // 512 partition blocks + 2*32 W1-pack + 2*128 W2-pack = 832 blocks
    prep_kernel<<<832, 256, 0, stream>>>(types, mol_id, W1A, W1B, W2A, W2B,
                                         cnt, perm, mol_cnt,
                                         W1FA, W1FB, W2FA, W2FB);
    mlp_kernel<<<2 * NB_SIDE, 256, 0, stream>>>(
        Gs, mol_id,
        W1FA, W2FA, b1A, b2A, W3A, b3A, oA,
        W1FB, W2FB, b1B, b2B, W3B, b3B, oB,
        cnt, perm, mol_sum);
    finalize_kernel<<<(N_MOL + 255) / 256, 256, 0, stream>>>(mol_sum, mol_cnt, out);
}

// Round 5
// 389.637 us; speedup vs baseline: 4.1517x; 1.2714x over previous
//
#include <hip/hip_runtime.h>

typedef _Float16 half8  __attribute__((ext_vector_type(8)));
typedef _Float16 half4  __attribute__((ext_vector_type(4)));
typedef float    floatx4 __attribute__((ext_vector_type(4)));

#define N_ATOMS 131072
#define NUM_GS  128
#define HIDDEN  512
#define N_MOL   1024

#define BM      32                      // atoms per MLP block
#define NB_SIDE (N_ATOMS / BM)          // 4096 blocks per type-side
#define NT_TOT  (HIDDEN / 16)           // 32 n-tiles in fragment layout
#define SH1_LD  (HIDDEN + 8)            // sH1 leading dim (halves)

// ---- workspace byte offsets ----
#define WS_CNT_OFF     0               // int[2]
#define WS_MOLSUM_OFF  1024            // float[1024]
#define WS_MOLCNT_OFF  5120            // float[1024]
#define WS_PERM_OFF    9216            // int[131072]
#define WS_W1FA_OFF    533504          // fp16 frags 512*128
#define WS_W1FB_OFF    664576
#define WS_W2FA_OFF    795648          // fp16 frags 512*512
#define WS_W2FB_OFF    1319936
#define WS_ZERO_BYTES  9216

__device__ __forceinline__ float fast_tanh(float x) {
    x = fminf(20.f, fmaxf(-20.f, x));
    float e = __expf(2.f * x);
    return (e - 1.f) / (e + 1.f);
}

// ---------------------------------------------------------------------------
// Fused prep kernel (one dispatch):
//  blocks [0,512)    : partition atoms by type + per-molecule counts
//  blocks [512,832)  : pack W1/W2 fp32 [K][512] -> fp16 MFMA B-fragment layout
//                      [ktile][ntile][lane][8]; mlp B-loads become one
//                      coalesced 1KB dwordx4 per wave.
//                      Element: n = ntile*16 + (lane&15), k = ktile*32 + (lane>>4)*8 + j.
// ---------------------------------------------------------------------------
__global__ __launch_bounds__(256)
void prep_kernel(const int* __restrict__ types,
                 const int* __restrict__ mol_id,
                 const float* __restrict__ W1A, const float* __restrict__ W1B,
                 const float* __restrict__ W2A, const float* __restrict__ W2B,
                 int* __restrict__ cnt, int* __restrict__ perm,
                 float* __restrict__ mol_cnt,
                 _Float16* __restrict__ W1FA, _Float16* __restrict__ W1FB,
                 _Float16* __restrict__ W2FA, _Float16* __restrict__ W2FB) {
    __shared__ float tile[32][65];
    const int p   = blockIdx.x;
    const int tid = threadIdx.x;

    if (p < 512) {                      // ---- partition ----
        int i = p * 256 + tid;
        if (types[i] == 0) {
            int q = atomicAdd(&cnt[0], 1);
            perm[q] = i;
        } else {
            int q = atomicAdd(&cnt[1], 1);
            perm[N_ATOMS - 1 - q] = i;
        }
        atomicAdd(&mol_cnt[mol_id[i]], 1.0f);
        return;
    }

    // ---- weight pack: block handles K=32 x N=64 region ----
    const float* src; _Float16* dst; int pb;
    if (p < 544)      { src = W1A; dst = W1FA; pb = p - 512; }
    else if (p < 576) { src = W1B; dst = W1FB; pb = p - 544; }
    else if (p < 704) { src = W2A; dst = W2FA; pb = p - 576; }
    else              { src = W2B; dst = W2FB; pb = p - 704; }
    const int bx = pb & 7;              // n-block (8 per row of 512)
    const int by = pb >> 3;             // ktile
    const int n0 = bx * 64, k0 = by * 32;
    #pragma unroll
    for (int i = 0; i < 8; ++i) {
        int idx = tid + i * 256;
        int r = idx >> 6, c = idx & 63;
        tile[r][c] = src[(size_t)(k0 + r) * HIDDEN + n0 + c];
    }
    __syncthreads();
    const int nt_l = tid >> 6, lane = tid & 63;
    const int l15 = lane & 15, q = lane >> 4;
    half8 v;
    #pragma unroll
    for (int j = 0; j < 8; ++j)
        v[j] = (_Float16)tile[q * 8 + j][nt_l * 16 + l15];
    const int ntile = bx * 4 + nt_l;
    *(half8*)(dst + (((size_t)by * NT_TOT + ntile) * 64 + lane) * 8) = v;
}

// ---------------------------------------------------------------------------
// Fused per-type MLP, f16 MFMA. BM=32 atoms/block, 4 waves; wave w owns
// cols [128w, 128w+128) in BOTH layers. acc[2][8]=64 regs -> ~150 total
// -> 3 waves/SIMD; LDS ~43 KB -> 3 blocks/CU. Full sH1 resident: layer1 is
// one shot (no chunk loop), single barrier before layer2's K=512 sweep.
// ---------------------------------------------------------------------------
__global__ __launch_bounds__(256, 3)
void mlp_kernel(const float* __restrict__ Gs,
                const int*   __restrict__ mol_id,
                const _Float16* __restrict__ W1FA, const _Float16* __restrict__ W2FA,
                const float* __restrict__ b1A, const float* __restrict__ b2A,
                const float* __restrict__ W3A, const float* __restrict__ b3A,
                const float* __restrict__ offA,
                const _Float16* __restrict__ W1FB, const _Float16* __restrict__ W2FB,
                const float* __restrict__ b1B, const float* __restrict__ b2B,
                const float* __restrict__ W3B, const float* __restrict__ b3B,
                const float* __restrict__ offB,
                const int* __restrict__ cnt, const int* __restrict__ perm,
                float* __restrict__ mol_sum) {
    __shared__ __align__(16) _Float16 sGh[BM][NUM_GS + 8];   // 8.5 KB
    __shared__ __align__(16) _Float16 sH1[BM][SH1_LD];       // 32.5 KB
    __shared__ int   sOrig[BM];
    __shared__ float sPart[4][BM];

    const int b     = blockIdx.x;
    const int nA    = cnt[0];
    const int sideB = (b >= NB_SIDE) ? 1 : 0;
    const int r0    = (sideB ? b - NB_SIDE : b) * BM;
    const int nSide = sideB ? (N_ATOMS - nA) : nA;
    if (r0 >= nSide) return;

    const _Float16 *W1F, *W2F;
    const float *b1, *b2, *W3;
    float b3off;
    if (!sideB) { W1F = W1FA; W2F = W2FA; b1 = b1A; b2 = b2A; W3 = W3A; b3off = b3A[0] + offA[0]; }
    else        { W1F = W1FB; W2F = W2FB; b1 = b1B; b2 = b2B; W3 = W3B; b3off = b3B[0] + offB[0]; }

    const int tid = threadIdx.x;
    if (tid < BM) {
        int r = r0 + tid;
        int orig = -1;
        if (r < nSide) orig = sideB ? perm[N_ATOMS - 1 - r] : perm[r];
        sOrig[tid] = orig;
    }
    __syncthreads();

    // ---- stage G tile (fp32 -> fp16): 32 rows x 128 cols = 1024 float4
    #pragma unroll
    for (int i = 0; i < 4; ++i) {
        int idx = tid + 256 * i;
        int row = idx >> 5;             // 32 float4 per row
        int c4  = idx & 31;
        int orig = sOrig[row];
        float4 v = make_float4(0.f, 0.f, 0.f, 0.f);
        if (orig >= 0) v = ((const float4*)(Gs + (size_t)orig * NUM_GS))[c4];
        half4 h; h[0] = (_Float16)v.x; h[1] = (_Float16)v.y;
                 h[2] = (_Float16)v.z; h[3] = (_Float16)v.w;
        *(half4*)&sGh[row][c4 * 4] = h;
    }
    __syncthreads();

    const int lane = tid & 63;
    const int wid  = tid >> 6;          // wave owns cols [128*wid, 128*wid+128)
    const int l15  = lane & 15;
    const int quad = lane >> 4;

    floatx4 acc[2][8];
    #pragma unroll
    for (int mt = 0; mt < 2; ++mt)
        #pragma unroll
        for (int nt = 0; nt < 8; ++nt) acc[mt][nt] = (floatx4){0.f, 0.f, 0.f, 0.f};

    // ================= layer 1: H1 = tanh(G @ W1 + b1), K=128 =================
    #pragma unroll
    for (int ks = 0; ks < NUM_GS / 32; ++ks) {
        half8 a0 = *(const half8*)&sGh[l15][ks * 32 + quad * 8];
        half8 a1 = *(const half8*)&sGh[l15 + 16][ks * 32 + quad * 8];
        #pragma unroll
        for (int nt = 0; nt < 8; ++nt) {
            int ntile = wid * 8 + nt;
            half8 bf = *(const half8*)(W1F + (((size_t)ks * NT_TOT + ntile) * 64 + lane) * 8);
            acc[0][nt] = __builtin_amdgcn_mfma_f32_16x16x32_f16(a0, bf, acc[0][nt], 0, 0, 0);
            acc[1][nt] = __builtin_amdgcn_mfma_f32_16x16x32_f16(a1, bf, acc[1][nt], 0, 0, 0);
        }
    }
    #pragma unroll
    for (int nt = 0; nt < 8; ++nt) {
        int col = wid * 128 + nt * 16 + l15;
        float b1v = b1[col];
        #pragma unroll
        for (int mt = 0; mt < 2; ++mt)
            #pragma unroll
            for (int r = 0; r < 4; ++r)
                sH1[mt * 16 + quad * 4 + r][col] = (_Float16)fast_tanh(acc[mt][nt][r] + b1v);
    }
    __syncthreads();

    // ================= layer 2: pre2 = H1 @ W2 + b2, K=512 =================
    #pragma unroll
    for (int mt = 0; mt < 2; ++mt)
        #pragma unroll
        for (int nt = 0; nt < 8; ++nt) acc[mt][nt] = (floatx4){0.f, 0.f, 0.f, 0.f};

    #pragma unroll 4
    for (int ks = 0; ks < HIDDEN / 32; ++ks) {
        half8 a0 = *(const half8*)&sH1[l15][ks * 32 + quad * 8];
        half8 a1 = *(const half8*)&sH1[l15 + 16][ks * 32 + quad * 8];
        #pragma unroll
        for (int nt = 0; nt < 8; ++nt) {
            int ntile = wid * 8 + nt;
            half8 bf = *(const half8*)(W2F + (((size_t)ks * NT_TOT + ntile) * 64 + lane) * 8);
            acc[0][nt] = __builtin_amdgcn_mfma_f32_16x16x32_f16(a0, bf, acc[0][nt], 0, 0, 0);
            acc[1][nt] = __builtin_amdgcn_mfma_f32_16x16x32_f16(a1, bf, acc[1][nt], 0, 0, 0);
        }
    }

    // ======== layer 3 fused: e = sum_j tanh(pre2_j)*W3_j + b3 + off ========
    float p[2][4];
    #pragma unroll
    for (int mt = 0; mt < 2; ++mt)
        #pragma unroll
        for (int r = 0; r < 4; ++r) p[mt][r] = 0.f;

    #pragma unroll
    for (int nt = 0; nt < 8; ++nt) {
        int col = wid * 128 + nt * 16 + l15;
        float b2v = b2[col];
        float w3v = W3[col];
        #pragma unroll
        for (int mt = 0; mt < 2; ++mt)
            #pragma unroll
            for (int r = 0; r < 4; ++r)
                p[mt][r] += fast_tanh(acc[mt][nt][r] + b2v) * w3v;
    }
    #pragma unroll
    for (int mt = 0; mt < 2; ++mt)
        #pragma unroll
        for (int r = 0; r < 4; ++r) {
            float v = p[mt][r];
            v += __shfl_xor(v, 1, 64);
            v += __shfl_xor(v, 2, 64);
            v += __shfl_xor(v, 4, 64);
            v += __shfl_xor(v, 8, 64);
            p[mt][r] = v;
        }
    if (l15 == 0) {
        #pragma unroll
        for (int mt = 0; mt < 2; ++mt)
            #pragma unroll
            for (int r = 0; r < 4; ++r)
                sPart[wid][mt * 16 + quad * 4 + r] = p[mt][r];
    }
    __syncthreads();
    if (tid < BM) {
        int orig = sOrig[tid];
        if (orig >= 0) {
            float e = sPart[0][tid] + sPart[1][tid] + sPart[2][tid] + sPart[3][tid] + b3off;
            atomicAdd(&mol_sum[mol_id[orig]], e);
        }
    }
}

// ---------------------------------------------------------------------------
// finalize: per-molecule mean
// ---------------------------------------------------------------------------
__global__ void finalize_kernel(const float* __restrict__ mol_sum,
                                const float* __restrict__ mol_cnt,
                                float* __restrict__ out) {
    int m = blockIdx.x * blockDim.x + threadIdx.x;
    if (m >= N_MOL) return;
    out[m] = mol_sum[m] / fmaxf(mol_cnt[m], 1.0f);
}

extern "C" void kernel_launch(void* const* d_in, const int* in_sizes, int n_in,
                              void* d_out, int out_size, void* d_ws, size_t ws_size,
                              hipStream_t stream) {
    const float* Gs     = (const float*)d_in[0];
    const int*   types  = (const int*)d_in[1];
    const int*   mol_id = (const int*)d_in[2];
    const float* W1A = (const float*)d_in[3];
    const float* b1A = (const float*)d_in[4];
    const float* W2A = (const float*)d_in[5];
    const float* b2A = (const float*)d_in[6];
    const float* W3A = (const float*)d_in[7];
    const float* b3A = (const float*)d_in[8];
    const float* oA  = (const float*)d_in[9];
    const float* W1B = (const float*)d_in[10];
    const float* b1B = (const float*)d_in[11];
    const float* W2B = (const float*)d_in[12];
    const float* b2B = (const float*)d_in[13];
    const float* W3B = (const float*)d_in[14];
    const float* b3B = (const float*)d_in[15];
    const float* oB  = (const float*)d_in[16];

    char* ws = (char*)d_ws;
    int*      cnt     = (int*)(ws + WS_CNT_OFF);
    float*    mol_sum = (float*)(ws + WS_MOLSUM_OFF);
    float*    mol_cnt = (float*)(ws + WS_MOLCNT_OFF);
    int*      perm    = (int*)(ws + WS_PERM_OFF);
    _Float16* W1FA    = (_Float16*)(ws + WS_W1FA_OFF);
    _Float16* W1FB    = (_Float16*)(ws + WS_W1FB_OFF);
    _Float16* W2FA    = (_Float16*)(ws + WS_W2FA_OFF);
    _Float16* W2FB    = (_Float16*)(ws + WS_W2FB_OFF);
    float* out = (float*)d_out;

    hipMemsetAsync(d_ws, 0, WS_ZERO_BYTES, stream);
    // 512 partition blocks + 2*32 W1-pack + 2*128 W2-pack = 832 blocks
    prep_kernel<<<832, 256, 0, stream>>>(types, mol_id, W1A, W1B, W2A, W2B,
                                         cnt, perm, mol_cnt,
                                         W1FA, W1FB, W2FA, W2FB);
    mlp_kernel<<<2 * NB_SIDE, 256, 0, stream>>>(
        Gs, mol_id,
        W1FA, W2FA, b1A, b2A, W3A, b3A, oA,
        W1FB, W2FB, b1B, b2B, W3B, b3B, oB,
        cnt, perm, mol_sum);
    finalize_kernel<<<(N_MOL + 255) / 256, 256, 0, stream>>>(mol_sum, mol_cnt, out);
}

// Round 6
// 299.037 us; speedup vs baseline: 5.4095x; 1.3030x over previous
//
#include <hip/hip_runtime.h>

typedef _Float16 half8  __attribute__((ext_vector_type(8)));
typedef _Float16 half4  __attribute__((ext_vector_type(4)));
typedef float    floatx4 __attribute__((ext_vector_type(4)));

#define N_ATOMS 131072
#define NUM_GS  128
#define HIDDEN  512
#define N_MOL   1024

#define BM      32                      // atoms per MLP block
#define NB_SIDE (N_ATOMS / BM)          // 4096 blocks per type-side
#define NT_TOT  (HIDDEN / 16)           // 32 n-tiles in fragment layout
#define SH1_LD  (HIDDEN + 8)            // sH1 leading dim (halves)

// ---- workspace byte offsets ----
#define WS_CNT_OFF     0               // int[2]
#define WS_MOLSUM_OFF  1024            // float[1024]
#define WS_PERM_OFF    9216            // int[131072]
#define WS_W1FA_OFF    533504          // fp16 frags 512*128
#define WS_W1FB_OFF    664576
#define WS_W2FA_OFF    795648          // fp16 frags 512*512
#define WS_W2FB_OFF    1319936
#define WS_ZERO_BYTES  5120            // cnt + mol_sum

__device__ __forceinline__ float fast_tanh(float x) {
    x = fminf(20.f, fmaxf(-20.f, x));
    float e = __expf(2.f * x);
    return (e - 1.f) / (e + 1.f);
}

// ---------------------------------------------------------------------------
// Fused prep kernel (one dispatch):
//  blocks [0,512)  : partition atoms by type. Per-wave ballot rank + LDS
//                    wave prefix; exactly 2 global atomics per block (was
//                    131k per-atom atomics -- the sorted mol_id made the
//                    old per-atom mol_cnt atomicAdd 64-way same-address
//                    serialized, ~190 us). Counts now come from binary
//                    search in finalize (mol_id is sorted).
//  blocks [512,832): pack W1/W2 fp32 [K][512] -> fp16 MFMA B-fragment layout
//                    [ktile][ntile][lane][8] (coalesced 1KB loads in mlp).
// ---------------------------------------------------------------------------
__global__ __launch_bounds__(256)
void prep_kernel(const int* __restrict__ types,
                 const float* __restrict__ W1A, const float* __restrict__ W1B,
                 const float* __restrict__ W2A, const float* __restrict__ W2B,
                 int* __restrict__ cnt, int* __restrict__ perm,
                 _Float16* __restrict__ W1FA, _Float16* __restrict__ W1FB,
                 _Float16* __restrict__ W2FA, _Float16* __restrict__ W2FB) {
    __shared__ float tile[32][65];
    const int p   = blockIdx.x;
    const int tid = threadIdx.x;

    if (p < 512) {                      // ---- partition, 2 atomics/block ----
        __shared__ int sCA[4];
        __shared__ int sBaseA, sBaseB;
        const int i    = p * 256 + tid;
        const int lane = tid & 63;
        const int w    = tid >> 6;
        const bool isA = (types[i] == 0);
        unsigned long long mask = __ballot(isA);
        unsigned long long lt   = ((unsigned long long)1 << lane) - 1;
        int rA = __popcll(mask & lt);   // rank among type-A in wave
        if (lane == 0) sCA[w] = __popcll(mask);
        __syncthreads();
        if (tid == 0) {
            int tot = sCA[0] + sCA[1] + sCA[2] + sCA[3];
            sBaseA = atomicAdd(&cnt[0], tot);
            sBaseB = atomicAdd(&cnt[1], 256 - tot);
        }
        __syncthreads();
        int preA = 0;
        #pragma unroll
        for (int k = 0; k < 4; ++k) preA += (k < w) ? sCA[k] : 0;
        int preB = w * 64 - preA;
        int rB   = lane - rA;
        if (isA) perm[sBaseA + preA + rA] = i;
        else     perm[N_ATOMS - 1 - (sBaseB + preB + rB)] = i;
        return;
    }

    // ---- weight pack: block handles K=32 x N=64 region ----
    const float* src; _Float16* dst; int pb;
    if (p < 544)      { src = W1A; dst = W1FA; pb = p - 512; }
    else if (p < 576) { src = W1B; dst = W1FB; pb = p - 544; }
    else if (p < 704) { src = W2A; dst = W2FA; pb = p - 576; }
    else              { src = W2B; dst = W2FB; pb = p - 704; }
    const int bx = pb & 7;              // n-block (8 per row of 512)
    const int by = pb >> 3;             // ktile
    const int n0 = bx * 64, k0 = by * 32;
    #pragma unroll
    for (int i = 0; i < 8; ++i) {
        int idx = tid + i * 256;
        int r = idx >> 6, c = idx & 63;
        tile[r][c] = src[(size_t)(k0 + r) * HIDDEN + n0 + c];
    }
    __syncthreads();
    const int nt_l = tid >> 6, lane = tid & 63;
    const int l15 = lane & 15, q = lane >> 4;
    half8 v;
    #pragma unroll
    for (int j = 0; j < 8; ++j)
        v[j] = (_Float16)tile[q * 8 + j][nt_l * 16 + l15];
    const int ntile = bx * 4 + nt_l;
    *(half8*)(dst + (((size_t)by * NT_TOT + ntile) * 64 + lane) * 8) = v;
}

// ---------------------------------------------------------------------------
// Fused per-type MLP, f16 MFMA. BM=32 atoms/block, 4 waves; wave w owns
// cols [128w, 128w+128) in BOTH layers. acc[2][8]=64 regs -> 3 waves/SIMD;
// LDS ~43 KB -> 3 blocks/CU. Full sH1 resident; single barrier before the
// uninterrupted K=512 layer-2 sweep. (unchanged from round 5)
// ---------------------------------------------------------------------------
__global__ __launch_bounds__(256, 3)
void mlp_kernel(const float* __restrict__ Gs,
                const int*   __restrict__ mol_id,
                const _Float16* __restrict__ W1FA, const _Float16* __restrict__ W2FA,
                const float* __restrict__ b1A, const float* __restrict__ b2A,
                const float* __restrict__ W3A, const float* __restrict__ b3A,
                const float* __restrict__ offA,
                const _Float16* __restrict__ W1FB, const _Float16* __restrict__ W2FB,
                const float* __restrict__ b1B, const float* __restrict__ b2B,
                const float* __restrict__ W3B, const float* __restrict__ b3B,
                const float* __restrict__ offB,
                const int* __restrict__ cnt, const int* __restrict__ perm,
                float* __restrict__ mol_sum) {
    __shared__ __align__(16) _Float16 sGh[BM][NUM_GS + 8];   // 8.5 KB
    __shared__ __align__(16) _Float16 sH1[BM][SH1_LD];       // 32.5 KB
    __shared__ int   sOrig[BM];
    __shared__ float sPart[4][BM];

    const int b     = blockIdx.x;
    const int nA    = cnt[0];
    const int sideB = (b >= NB_SIDE) ? 1 : 0;
    const int r0    = (sideB ? b - NB_SIDE : b) * BM;
    const int nSide = sideB ? (N_ATOMS - nA) : nA;
    if (r0 >= nSide) return;

    const _Float16 *W1F, *W2F;
    const float *b1, *b2, *W3;
    float b3off;
    if (!sideB) { W1F = W1FA; W2F = W2FA; b1 = b1A; b2 = b2A; W3 = W3A; b3off = b3A[0] + offA[0]; }
    else        { W1F = W1FB; W2F = W2FB; b1 = b1B; b2 = b2B; W3 = W3B; b3off = b3B[0] + offB[0]; }

    const int tid = threadIdx.x;
    if (tid < BM) {
        int r = r0 + tid;
        int orig = -1;
        if (r < nSide) orig = sideB ? perm[N_ATOMS - 1 - r] : perm[r];
        sOrig[tid] = orig;
    }
    __syncthreads();

    // ---- stage G tile (fp32 -> fp16): 32 rows x 128 cols = 1024 float4
    #pragma unroll
    for (int i = 0; i < 4; ++i) {
        int idx = tid + 256 * i;
        int row = idx >> 5;             // 32 float4 per row
        int c4  = idx & 31;
        int orig = sOrig[row];
        float4 v = make_float4(0.f, 0.f, 0.f, 0.f);
        if (orig >= 0) v = ((const float4*)(Gs + (size_t)orig * NUM_GS))[c4];
        half4 h; h[0] = (_Float16)v.x; h[1] = (_Float16)v.y;
                 h[2] = (_Float16)v.z; h[3] = (_Float16)v.w;
        *(half4*)&sGh[row][c4 * 4] = h;
    }
    __syncthreads();

    const int lane = tid & 63;
    const int wid  = tid >> 6;          // wave owns cols [128*wid, 128*wid+128)
    const int l15  = lane & 15;
    const int quad = lane >> 4;

    floatx4 acc[2][8];
    #pragma unroll
    for (int mt = 0; mt < 2; ++mt)
        #pragma unroll
        for (int nt = 0; nt < 8; ++nt) acc[mt][nt] = (floatx4){0.f, 0.f, 0.f, 0.f};

    // ================= layer 1: H1 = tanh(G @ W1 + b1), K=128 =================
    #pragma unroll
    for (int ks = 0; ks < NUM_GS / 32; ++ks) {
        half8 a0 = *(const half8*)&sGh[l15][ks * 32 + quad * 8];
        half8 a1 = *(const half8*)&sGh[l15 + 16][ks * 32 + quad * 8];
        #pragma unroll
        for (int nt = 0; nt < 8; ++nt) {
            int ntile = wid * 8 + nt;
            half8 bf = *(const half8*)(W1F + (((size_t)ks * NT_TOT + ntile) * 64 + lane) * 8);
            acc[0][nt] = __builtin_amdgcn_mfma_f32_16x16x32_f16(a0, bf, acc[0][nt], 0, 0, 0);
            acc[1][nt] = __builtin_amdgcn_mfma_f32_16x16x32_f16(a1, bf, acc[1][nt], 0, 0, 0);
        }
    }
    #pragma unroll
    for (int nt = 0; nt < 8; ++nt) {
        int col = wid * 128 + nt * 16 + l15;
        float b1v = b1[col];
        #pragma unroll
        for (int mt = 0; mt < 2; ++mt)
            #pragma unroll
            for (int r = 0; r < 4; ++r)
                sH1[mt * 16 + quad * 4 + r][col] = (_Float16)fast_tanh(acc[mt][nt][r] + b1v);
    }
    __syncthreads();

    // ================= layer 2: pre2 = H1 @ W2 + b2, K=512 =================
    #pragma unroll
    for (int mt = 0; mt < 2; ++mt)
        #pragma unroll
        for (int nt = 0; nt < 8; ++nt) acc[mt][nt] = (floatx4){0.f, 0.f, 0.f, 0.f};

    #pragma unroll 4
    for (int ks = 0; ks < HIDDEN / 32; ++ks) {
        half8 a0 = *(const half8*)&sH1[l15][ks * 32 + quad * 8];
        half8 a1 = *(const half8*)&sH1[l15 + 16][ks * 32 + quad * 8];
        #pragma unroll
        for (int nt = 0; nt < 8; ++nt) {
            int ntile = wid * 8 + nt;
            half8 bf = *(const half8*)(W2F + (((size_t)ks * NT_TOT + ntile) * 64 + lane) * 8);
            acc[0][nt] = __builtin_amdgcn_mfma_f32_16x16x32_f16(a0, bf, acc[0][nt], 0, 0, 0);
            acc[1][nt] = __builtin_amdgcn_mfma_f32_16x16x32_f16(a1, bf, acc[1][nt], 0, 0, 0);
        }
    }

    // ======== layer 3 fused: e = sum_j tanh(pre2_j)*W3_j + b3 + off ========
    float p[2][4];
    #pragma unroll
    for (int mt = 0; mt < 2; ++mt)
        #pragma unroll
        for (int r = 0; r < 4; ++r) p[mt][r] = 0.f;

    #pragma unroll
    for (int nt = 0; nt < 8; ++nt) {
        int col = wid * 128 + nt * 16 + l15;
        float b2v = b2[col];
        float w3v = W3[col];
        #pragma unroll
        for (int mt = 0; mt < 2; ++mt)
            #pragma unroll
            for (int r = 0; r < 4; ++r)
                p[mt][r] += fast_tanh(acc[mt][nt][r] + b2v) * w3v;
    }
    #pragma unroll
    for (int mt = 0; mt < 2; ++mt)
        #pragma unroll
        for (int r = 0; r < 4; ++r) {
            float v = p[mt][r];
            v += __shfl_xor(v, 1, 64);
            v += __shfl_xor(v, 2, 64);
            v += __shfl_xor(v, 4, 64);
            v += __shfl_xor(v, 8, 64);
            p[mt][r] = v;
        }
    if (l15 == 0) {
        #pragma unroll
        for (int mt = 0; mt < 2; ++mt)
            #pragma unroll
            for (int r = 0; r < 4; ++r)
                sPart[wid][mt * 16 + quad * 4 + r] = p[mt][r];
    }
    __syncthreads();
    if (tid < BM) {
        int orig = sOrig[tid];
        if (orig >= 0) {
            float e = sPart[0][tid] + sPart[1][tid] + sPart[2][tid] + sPart[3][tid] + b3off;
            atomicAdd(&mol_sum[mol_id[orig]], e);
        }
    }
}

// ---------------------------------------------------------------------------
// finalize: per-molecule mean; counts via binary search in sorted mol_id
// (replaces 131k colliding atomics with 2x17 L2 loads per molecule).
// ---------------------------------------------------------------------------
__global__ void finalize_kernel(const float* __restrict__ mol_sum,
                                const int* __restrict__ mol_id,
                                float* __restrict__ out) {
    int m = blockIdx.x * blockDim.x + threadIdx.x;
    if (m >= N_MOL) return;
    int lo0 = 0, hi0 = N_ATOMS;         // lower_bound(m)
    while (lo0 < hi0) { int mid = (lo0 + hi0) >> 1; if (mol_id[mid] < m) lo0 = mid + 1; else hi0 = mid; }
    int lo1 = lo0, hi1 = N_ATOMS;       // lower_bound(m+1)
    while (lo1 < hi1) { int mid = (lo1 + hi1) >> 1; if (mol_id[mid] < m + 1) lo1 = mid + 1; else hi1 = mid; }
    float c = (float)(lo1 - lo0);
    out[m] = mol_sum[m] / fmaxf(c, 1.0f);
}

extern "C" void kernel_launch(void* const* d_in, const int* in_sizes, int n_in,
                              void* d_out, int out_size, void* d_ws, size_t ws_size,
                              hipStream_t stream) {
    const float* Gs     = (const float*)d_in[0];
    const int*   types  = (const int*)d_in[1];
    const int*   mol_id = (const int*)d_in[2];
    const float* W1A = (const float*)d_in[3];
    const float* b1A = (const float*)d_in[4];
    const float* W2A = (const float*)d_in[5];
    const float* b2A = (const float*)d_in[6];
    const float* W3A = (const float*)d_in[7];
    const float* b3A = (const float*)d_in[8];
    const float* oA  = (const float*)d_in[9];
    const float* W1B = (const float*)d_in[10];
    const float* b1B = (const float*)d_in[11];
    const float* W2B = (const float*)d_in[12];
    const float* b2B = (const float*)d_in[13];
    const float* W3B = (const float*)d_in[14];
    const float* b3B = (const float*)d_in[15];
    const float* oB  = (const float*)d_in[16];

    char* ws = (char*)d_ws;
    int*      cnt     = (int*)(ws + WS_CNT_OFF);
    float*    mol_sum = (float*)(ws + WS_MOLSUM_OFF);
    int*      perm    = (int*)(ws + WS_PERM_OFF);
    _Float16* W1FA    = (_Float16*)(ws + WS_W1FA_OFF);
    _Float16* W1FB    = (_Float16*)(ws + WS_W1FB_OFF);
    _Float16* W2FA    = (_Float16*)(ws + WS_W2FA_OFF);
    _Float16* W2FB    = (_Float16*)(ws + WS_W2FB_OFF);
    float* out = (float*)d_out;

    hipMemsetAsync(d_ws, 0, WS_ZERO_BYTES, stream);
    // 512 partition blocks + 2*32 W1-pack + 2*128 W2-pack = 832 blocks
    prep_kernel<<<832, 256, 0, stream>>>(types, W1A, W1B, W2A, W2B,
                                         cnt, perm,
                                         W1FA, W1FB, W2FA, W2FB);
    mlp_kernel<<<2 * NB_SIDE, 256, 0, stream>>>(
        Gs, mol_id,
        W1FA, W2FA, b1A, b2A, W3A, b3A, oA,
        W1FB, W2FB, b1B, b2B, W3B, b3B, oB,
        cnt, perm, mol_sum);
    finalize_kernel<<<(N_MOL + 255) / 256, 256, 0, stream>>>(mol_sum, mol_id, out);
}